// Round 1
// baseline (1046.409 us; speedup 1.0000x reference)
//
#include <hip/hip_runtime.h>
#include <stdint.h>

#define H_    32
#define KV_   2
#define D_    128
#define HID_  4096
#define SQ_   1024
#define SMAX_ 4096

typedef unsigned short u16;
typedef __attribute__((ext_vector_type(8))) short bf16x8;
typedef __attribute__((ext_vector_type(8))) unsigned short u16x8;
typedef __attribute__((ext_vector_type(4))) float f32x4;

#define MFMA16(a, b, c) __builtin_amdgcn_mfma_f32_16x16x32_bf16(a, b, c, 0, 0, 0)

__device__ __forceinline__ u16 f2bf(float f) {
  unsigned u = __float_as_uint(f);
  u += 0x7fffu + ((u >> 16) & 1u);
  return (u16)(u >> 16);
}
__device__ __forceinline__ float bf2f(u16 u) {
  return __uint_as_float(((unsigned)u) << 16);
}

// ---------------------------------------------------------------------------
// hidden (HID x SQ) f32  ->  ht (SQ x HID) bf16   (transpose + convert)
__global__ __launch_bounds__(256) void k_ht(const float* __restrict__ hs,
                                            u16* __restrict__ ht) {
  __shared__ float tl[64][65];
  const int i0 = blockIdx.x << 6, s0 = blockIdx.y << 6;
  const int tid = threadIdx.x;
  {
    const int r = tid >> 2, c = (tid & 3) << 4;
    const float* p = hs + (i0 + r) * SQ_ + s0 + c;
    float4 a = *(const float4*)p;
    float4 b = *(const float4*)(p + 4);
    float4 cc = *(const float4*)(p + 8);
    float4 d = *(const float4*)(p + 12);
    float* q = &tl[r][c];
    q[0] = a.x; q[1] = a.y; q[2] = a.z; q[3] = a.w;
    q[4] = b.x; q[5] = b.y; q[6] = b.z; q[7] = b.w;
    q[8] = cc.x; q[9] = cc.y; q[10] = cc.z; q[11] = cc.w;
    q[12] = d.x; q[13] = d.y; q[14] = d.z; q[15] = d.w;
  }
  __syncthreads();
  {
    const int sr = tid >> 2, c = (tid & 3) << 4;
    u16x8 o0, o1;
#pragma unroll
    for (int j = 0; j < 8; ++j) o0[j] = f2bf(tl[c + j][sr]);
#pragma unroll
    for (int j = 0; j < 8; ++j) o1[j] = f2bf(tl[c + 8 + j][sr]);
    u16* q = ht + (s0 + sr) * HID_ + i0 + c;
    *(u16x8*)q = o0;
    *(u16x8*)(q + 8) = o1;
  }
}

// ---------------------------------------------------------------------------
// C[m][n] = sum_k A_f32[m][k] * B_bf16[n][k]  (+bias[m])
// OUTMODE 0: bf16 out at C[m*ldc+n];  1: bf16 out at C[m*ldc+cp+n];  2: f32 out
template <int OUTMODE>
__global__ __launch_bounds__(256) void k_gemm(const float* __restrict__ A,
                                              const float* __restrict__ bias,
                                              const u16* __restrict__ B,
                                              void* __restrict__ Cout,
                                              const int* __restrict__ cpp,
                                              int ldc) {
  __shared__ u16 a_t[128 * 32];
  __shared__ u16 b_t[128 * 32];
  const int n0 = blockIdx.x << 7, m0 = blockIdx.y << 7;
  const int tid = threadIdx.x;
  const int wid = tid >> 6, lane = tid & 63;
  const int l15 = lane & 15, l4 = lane >> 4;
  const int wm = (wid >> 1) * 64, wn = (wid & 1) * 64;

  const f32x4 z4 = {0.f, 0.f, 0.f, 0.f};
  f32x4 acc[4][4];
#pragma unroll
  for (int i = 0; i < 4; ++i)
#pragma unroll
    for (int j = 0; j < 4; ++j) acc[i][j] = z4;

  const int arow = tid >> 1, ac = (tid & 1) << 4;
  const float* Ap = A + (m0 + arow) * HID_ + ac;
  const u16* Bp = B + (n0 + arow) * HID_ + ac;

  for (int kt = 0; kt < HID_ / 32; ++kt) {
    float4 f0 = *(const float4*)(Ap);
    float4 f1 = *(const float4*)(Ap + 4);
    float4 f2 = *(const float4*)(Ap + 8);
    float4 f3 = *(const float4*)(Ap + 12);
    uint4 b0 = *(const uint4*)(Bp);
    uint4 b1 = *(const uint4*)(Bp + 8);
    Ap += 32;
    Bp += 32;
    u16x8 ua0, ua1;
    ua0[0] = f2bf(f0.x); ua0[1] = f2bf(f0.y); ua0[2] = f2bf(f0.z); ua0[3] = f2bf(f0.w);
    ua0[4] = f2bf(f1.x); ua0[5] = f2bf(f1.y); ua0[6] = f2bf(f1.z); ua0[7] = f2bf(f1.w);
    ua1[0] = f2bf(f2.x); ua1[1] = f2bf(f2.y); ua1[2] = f2bf(f2.z); ua1[3] = f2bf(f2.w);
    ua1[4] = f2bf(f3.x); ua1[5] = f2bf(f3.y); ua1[6] = f2bf(f3.z); ua1[7] = f2bf(f3.w);
    __syncthreads();
    *(u16x8*)&a_t[arow * 32 + ac] = ua0;
    *(u16x8*)&a_t[arow * 32 + ac + 8] = ua1;
    *(uint4*)&b_t[arow * 32 + ac] = b0;
    *(uint4*)&b_t[arow * 32 + ac + 8] = b1;
    __syncthreads();
    bf16x8 af[4];
#pragma unroll
    for (int mf = 0; mf < 4; ++mf)
      af[mf] = *(const bf16x8*)&a_t[(wm + mf * 16 + l15) * 32 + l4 * 8];
#pragma unroll
    for (int nf = 0; nf < 4; ++nf) {
      bf16x8 bf = *(const bf16x8*)&b_t[(wn + nf * 16 + l15) * 32 + l4 * 8];
#pragma unroll
      for (int mf = 0; mf < 4; ++mf) acc[mf][nf] = MFMA16(af[mf], bf, acc[mf][nf]);
    }
  }

  const int coff = (OUTMODE == 1) ? cpp[0] : 0;
#pragma unroll
  for (int mf = 0; mf < 4; ++mf) {
#pragma unroll
    for (int r = 0; r < 4; ++r) {
      const int m = m0 + wm + mf * 16 + l4 * 4 + r;
      const float bi = bias ? bias[m] : 0.f;
#pragma unroll
      for (int nf = 0; nf < 4; ++nf) {
        const int n = n0 + wn + nf * 16 + l15;
        const float v = acc[mf][nf][r] + bi;
        if (OUTMODE == 2)
          ((float*)Cout)[m * ldc + n] = v;
        else
          ((u16*)Cout)[m * ldc + n + coff] = f2bf(v);
      }
    }
  }
}

// ---------------------------------------------------------------------------
// RoPE on q (rotate along d, tables cos_t/sin_t are [d][s]), transpose to (h,s,d)
__global__ __launch_bounds__(256) void k_rope_q(const u16* __restrict__ qnr,
                                                const float* __restrict__ cost,
                                                const float* __restrict__ sint,
                                                u16* __restrict__ Qr) {
  __shared__ u16 qt[128 * 64];
  __shared__ float ct[128 * 64];
  __shared__ float st[128 * 64];
  const int s0 = blockIdx.x << 6, h = blockIdx.y;
  const int tid = threadIdx.x;
  {
    const int r = tid >> 1, c = (tid & 1) << 5;
    const u16* p = qnr + (h * 128 + r) * SQ_ + s0 + c;
#pragma unroll
    for (int j = 0; j < 4; ++j) *(uint4*)&qt[r * 64 + c + j * 8] = *(const uint4*)(p + j * 8);
    const float* cpr = cost + r * SQ_ + s0 + c;
    const float* spr = sint + r * SQ_ + s0 + c;
#pragma unroll
    for (int j = 0; j < 8; ++j) {
      *(float4*)&ct[r * 64 + c + j * 4] = *(const float4*)(cpr + j * 4);
      *(float4*)&st[r * 64 + c + j * 4] = *(const float4*)(spr + j * 4);
    }
  }
  __syncthreads();
  const int sl = tid >> 2, d0 = (tid & 3) << 5;
  u16* op = Qr + (((h << 10) + s0 + sl) << 7) + d0;
#pragma unroll
  for (int g = 0; g < 4; ++g) {
    u16x8 o;
#pragma unroll
    for (int j = 0; j < 8; ++j) {
      const int d = d0 + g * 8 + j;
      const float v = bf2f(qt[d * 64 + sl]);
      const float vp = bf2f(qt[(d ^ 64) * 64 + sl]);
      const float sgn = (d < 64) ? -1.f : 1.f;
      o[j] = f2bf(v * ct[d * 64 + sl] + sgn * vp * st[d * 64 + sl]);
    }
    *(u16x8*)(op + g * 8) = o;
  }
}

// RoPE on k (tables cos/sin are [s][d]), scatter to k_full[kk][cp+s][d]
__global__ __launch_bounds__(256) void k_rope_k(const u16* __restrict__ knr,
                                                const float* __restrict__ cosp,
                                                const float* __restrict__ sinp,
                                                const int* __restrict__ cpp,
                                                u16* __restrict__ kful) {
  __shared__ u16 kt_[128 * 64];
  const int s0 = blockIdx.x << 6, kk = blockIdx.y;
  const int cp = cpp[0];
  const int tid = threadIdx.x;
  {
    const int r = tid >> 1, c = (tid & 1) << 5;
    const u16* p = knr + (kk * 128 + r) * SQ_ + s0 + c;
#pragma unroll
    for (int j = 0; j < 4; ++j) *(uint4*)&kt_[r * 64 + c + j * 8] = *(const uint4*)(p + j * 8);
  }
  __syncthreads();
  const int sl = tid >> 2, d0 = (tid & 3) << 5;
  const int s = s0 + sl;
  const float* crow = cosp + s * D_;
  const float* srow = sinp + s * D_;
  u16* op = kful + ((kk * SMAX_ + cp + s) << 7) + d0;
#pragma unroll
  for (int g = 0; g < 4; ++g) {
    u16x8 o;
#pragma unroll
    for (int j = 0; j < 8; ++j) {
      const int d = d0 + g * 8 + j;
      const float v = bf2f(kt_[d * 64 + sl]);
      const float vp = bf2f(kt_[(d ^ 64) * 64 + sl]);
      const float sgn = (d < 64) ? -1.f : 1.f;
      o[j] = f2bf(v * crow[d] + sgn * vp * srow[d]);
    }
    *(u16x8*)(op + g * 8) = o;
  }
}

// key_cache[0] prefix (s<cp) -> k_full bf16 (same layout)
__global__ __launch_bounds__(256) void k_prefk(const float* __restrict__ kc,
                                               const int* __restrict__ cpp,
                                               u16* __restrict__ kful) {
  const int cp = cpp[0];
  const int idx = (blockIdx.x << 8) + threadIdx.x;
  const int base = idx << 3;
  const int s = (base >> 7) & (SMAX_ - 1);
  if (s >= cp) return;
  const float* p = kc + base;
  float4 a = *(const float4*)p;
  float4 b = *(const float4*)(p + 4);
  u16x8 o;
  o[0] = f2bf(a.x); o[1] = f2bf(a.y); o[2] = f2bf(a.z); o[3] = f2bf(a.w);
  o[4] = f2bf(b.x); o[5] = f2bf(b.y); o[6] = f2bf(b.z); o[7] = f2bf(b.w);
  *(u16x8*)(kful + base) = o;
}

// value_cache[0] prefix (s<cp) -> v_t[kk][d][s] bf16 (transposed)
__global__ __launch_bounds__(256) void k_prefvt(const float* __restrict__ vc,
                                                const int* __restrict__ cpp,
                                                u16* __restrict__ vt) {
  const int cp = cpp[0];
  const int s0 = blockIdx.x << 6, d0 = blockIdx.y << 6, kk = blockIdx.z;
  if (s0 >= cp) return;
  __shared__ float tl[64][65];
  const int tid = threadIdx.x;
  {
    const int r = tid >> 2, c = (tid & 3) << 4;
    if (s0 + r < cp) {
      const float* p = vc + ((kk * SMAX_ + s0 + r) << 7) + d0 + c;
#pragma unroll
      for (int j = 0; j < 4; ++j) {
        float4 v = *(const float4*)(p + j * 4);
        tl[r][c + j * 4 + 0] = v.x;
        tl[r][c + j * 4 + 1] = v.y;
        tl[r][c + j * 4 + 2] = v.z;
        tl[r][c + j * 4 + 3] = v.w;
      }
    }
  }
  __syncthreads();
  const int dl = tid >> 2, c = (tid & 3) << 4;
  u16* op = vt + (kk * D_ + d0 + dl) * SMAX_ + s0 + c;
  if (s0 + c + 15 < cp) {
    u16x8 o0, o1;
#pragma unroll
    for (int j = 0; j < 8; ++j) o0[j] = f2bf(tl[c + j][dl]);
#pragma unroll
    for (int j = 0; j < 8; ++j) o1[j] = f2bf(tl[c + 8 + j][dl]);
    *(u16x8*)op = o0;
    *(u16x8*)(op + 8) = o1;
  } else {
#pragma unroll
    for (int j = 0; j < 16; ++j)
      if (s0 + c + j < cp) op[j] = f2bf(tl[c + j][dl]);
  }
}

// ---------------------------------------------------------------------------
// Flash attention: block=(head, 128-q tile), 4 waves x 32 q-rows, KV tiles of 64
__global__ __launch_bounds__(256) void k_attn(const u16* __restrict__ Q,
                                              const u16* __restrict__ Kf,
                                              const u16* __restrict__ Vt,
                                              const int* __restrict__ cpp,
                                              u16* __restrict__ Ob) {
  __shared__ u16 p_lds[4][32 * 64];
  const int h = blockIdx.x, qb = blockIdx.y;
  const int cp = cpp[0];
  const int kk = h >> 4;
  const int tid = threadIdx.x, wid = tid >> 6, lane = tid & 63;
  const int l15 = lane & 15, l4 = lane >> 4;
  const int qrow_base = (qb << 7) + wid * 32;
  char* pl = (char*)&p_lds[wid][0];

  bf16x8 aq[2][4];
#pragma unroll
  for (int mf = 0; mf < 2; ++mf)
#pragma unroll
    for (int ks = 0; ks < 4; ++ks)
      aq[mf][ks] = *(const bf16x8*)&Q[(((h << 10) + qrow_base + mf * 16 + l15) << 7) + ks * 32 + l4 * 8];

  const f32x4 z4 = {0.f, 0.f, 0.f, 0.f};
  f32x4 oacc[2][8];
  float mrun[2][4], lrun[2][4];
#pragma unroll
  for (int mf = 0; mf < 2; ++mf) {
#pragma unroll
    for (int nf = 0; nf < 8; ++nf) oacc[mf][nf] = z4;
#pragma unroll
    for (int r = 0; r < 4; ++r) {
      mrun[mf][r] = -1e30f;
      lrun[mf][r] = 0.f;
    }
  }
  const int nt = (cp + qrow_base + 31 + 64) >> 6;
  const float sc = 0.08838834764831845f;  // 1/sqrt(128)

  for (int kt = 0; kt < nt; ++kt) {
    const int kv0 = kt << 6;
    f32x4 sa[2][4];
#pragma unroll
    for (int mf = 0; mf < 2; ++mf)
#pragma unroll
      for (int nf = 0; nf < 4; ++nf) sa[mf][nf] = z4;
#pragma unroll
    for (int ks = 0; ks < 4; ++ks) {
#pragma unroll
      for (int nf = 0; nf < 4; ++nf) {
        bf16x8 bk = *(const bf16x8*)&Kf[((kk * SMAX_ + kv0 + nf * 16 + l15) << 7) + ks * 32 + l4 * 8];
        sa[0][nf] = MFMA16(aq[0][ks], bk, sa[0][nf]);
        sa[1][nf] = MFMA16(aq[1][ks], bk, sa[1][nf]);
      }
    }
    const bool needmask = (kv0 + 63) > (cp + qrow_base);
#pragma unroll
    for (int mf = 0; mf < 2; ++mf) {
#pragma unroll
      for (int r = 0; r < 4; ++r) {
        const int qrow = qrow_base + mf * 16 + l4 * 4 + r;
        const int lim = cp + qrow;
        float x0 = sa[mf][0][r] * sc;
        float x1 = sa[mf][1][r] * sc;
        float x2 = sa[mf][2][r] * sc;
        float x3 = sa[mf][3][r] * sc;
        if (needmask) {
          if (kv0 + 0 + l15 > lim) x0 = -1e9f;
          if (kv0 + 16 + l15 > lim) x1 = -1e9f;
          if (kv0 + 32 + l15 > lim) x2 = -1e9f;
          if (kv0 + 48 + l15 > lim) x3 = -1e9f;
        }
        float pm = fmaxf(fmaxf(x0, x1), fmaxf(x2, x3));
        pm = fmaxf(pm, __shfl_xor(pm, 1));
        pm = fmaxf(pm, __shfl_xor(pm, 2));
        pm = fmaxf(pm, __shfl_xor(pm, 4));
        pm = fmaxf(pm, __shfl_xor(pm, 8));
        const float mnew = fmaxf(mrun[mf][r], pm);
        const float sf = __expf(mrun[mf][r] - mnew);
        mrun[mf][r] = mnew;
        const float p0 = __expf(x0 - mnew);
        const float p1 = __expf(x1 - mnew);
        const float p2 = __expf(x2 - mnew);
        const float p3 = __expf(x3 - mnew);
        float rs = p0 + p1 + p2 + p3;
        rs += __shfl_xor(rs, 1);
        rs += __shfl_xor(rs, 2);
        rs += __shfl_xor(rs, 4);
        rs += __shfl_xor(rs, 8);
        lrun[mf][r] = lrun[mf][r] * sf + rs;
#pragma unroll
        for (int nf = 0; nf < 8; ++nf) oacc[mf][nf][r] *= sf;
        const int row = mf * 16 + l4 * 4 + r;
        const unsigned rb = (unsigned)(row << 7);
        const unsigned sw = (unsigned)((row & 7) << 4);
        *(u16*)(pl + ((rb + (unsigned)((0 + l15) << 1)) ^ sw)) = f2bf(p0);
        *(u16*)(pl + ((rb + (unsigned)((16 + l15) << 1)) ^ sw)) = f2bf(p1);
        *(u16*)(pl + ((rb + (unsigned)((32 + l15) << 1)) ^ sw)) = f2bf(p2);
        *(u16*)(pl + ((rb + (unsigned)((48 + l15) << 1)) ^ sw)) = f2bf(p3);
      }
    }
    bf16x8 ap[2][2];
#pragma unroll
    for (int mf = 0; mf < 2; ++mf)
#pragma unroll
      for (int k2 = 0; k2 < 2; ++k2) {
        const int row = mf * 16 + l15;
        unsigned byte = (unsigned)((row << 7) + ((k2 * 32 + l4 * 8) << 1));
        byte ^= (unsigned)((row & 7) << 4);
        ap[mf][k2] = *(const bf16x8*)(pl + byte);
      }
#pragma unroll
    for (int nf = 0; nf < 8; ++nf) {
#pragma unroll
      for (int k2 = 0; k2 < 2; ++k2) {
        bf16x8 bv = *(const bf16x8*)&Vt[(kk * D_ + nf * 16 + l15) * SMAX_ + kv0 + k2 * 32 + l4 * 8];
        oacc[0][nf] = MFMA16(ap[0][k2], bv, oacc[0][nf]);
        oacc[1][nf] = MFMA16(ap[1][k2], bv, oacc[1][nf]);
      }
    }
  }
#pragma unroll
  for (int mf = 0; mf < 2; ++mf) {
    float inv[4];
#pragma unroll
    for (int r = 0; r < 4; ++r) inv[r] = 1.f / lrun[mf][r];
#pragma unroll
    for (int nf = 0; nf < 8; ++nf)
#pragma unroll
      for (int r = 0; r < 4; ++r) {
        const int qrow = qrow_base + mf * 16 + l4 * 4 + r;
        Ob[(qrow << 12) + (h << 7) + nf * 16 + l15] = f2bf(oacc[mf][nf][r] * inv[r]);
      }
  }
}

// ---------------------------------------------------------------------------
extern "C" void kernel_launch(void* const* d_in, const int* in_sizes, int n_in,
                              void* d_out, int out_size, void* d_ws, size_t ws_size,
                              hipStream_t stream) {
  const float* hs    = (const float*)d_in[0];
  const float* cosp  = (const float*)d_in[1];
  const float* sinp  = (const float*)d_in[2];
  const float* cost  = (const float*)d_in[3];
  const float* sint  = (const float*)d_in[4];
  // d_in[5] attention_mask: analytically reproduced (kv <= cp + q -> 0 else -1e9)
  const float* kcache = (const float*)d_in[6];
  const float* vcache = (const float*)d_in[7];
  const float* wq = (const float*)d_in[8];
  const float* bq = (const float*)d_in[9];
  const float* wk = (const float*)d_in[10];
  const float* bk = (const float*)d_in[11];
  const float* wv = (const float*)d_in[12];
  const float* bv = (const float*)d_in[13];
  const float* wo = (const float*)d_in[14];
  const int* cpp = (const int*)d_in[15];

  char* ws = (char*)d_ws;
  u16* ht   = (u16*)(ws);                       //  8.0 MB : hidden^T bf16 (SQ x HID)
  u16* qnr  = (u16*)(ws + 8388608);             //  8.0 MB : q pre-rope (HD x SQ)
  u16* Qr   = (u16*)(ws + 16777216);            //  8.0 MB : q roped (H,SQ,D)
  u16* knr  = (u16*)(ws + 25165824);            //  0.5 MB : k pre-rope (256 x SQ)
  u16* kful = (u16*)(ws + 25690112);            //  2.0 MB : K full (KV,SMAX,D)
  u16* vt   = (u16*)(ws + 27787264);            //  2.0 MB : V^T full (KV,D,SMAX)
  u16* Ob   = (u16*)(ws + 29884416);            //  8.0 MB : attn out (SQ x HD)

  k_ht<<<dim3(64, 16), 256, 0, stream>>>(hs, ht);
  k_gemm<0><<<dim3(8, 32), 256, 0, stream>>>(wq, bq, ht, (void*)qnr, nullptr, SQ_);
  k_gemm<0><<<dim3(8, 2), 256, 0, stream>>>(wk, bk, ht, (void*)knr, nullptr, SQ_);
  k_gemm<1><<<dim3(8, 2), 256, 0, stream>>>(wv, bv, ht, (void*)vt, cpp, SMAX_);
  k_rope_q<<<dim3(16, 32), 256, 0, stream>>>(qnr, cost, sint, Qr);
  k_rope_k<<<dim3(16, 2), 256, 0, stream>>>(knr, cosp, sinp, cpp, kful);
  k_prefk<<<dim3(512), 256, 0, stream>>>(kcache, cpp, kful);
  k_prefvt<<<dim3(64, 2, 2), 256, 0, stream>>>(vcache, cpp, vt);
  k_attn<<<dim3(32, 8), 256, 0, stream>>>(Qr, kful, vt, cpp, Ob);
  k_gemm<2><<<dim3(8, 32), 256, 0, stream>>>(wo, nullptr, Ob, d_out, nullptr, SQ_);
  (void)in_sizes; (void)n_in; (void)out_size; (void)ws_size;
}

// Round 2
// 571.981 us; speedup vs baseline: 1.8294x; 1.8294x over previous
//
#include <hip/hip_runtime.h>
#include <stdint.h>

#define H_    32
#define KV_   2
#define D_    128
#define HID_  4096
#define SQ_   1024
#define SMAX_ 4096

typedef unsigned short u16;
typedef __attribute__((ext_vector_type(8))) short bf16x8;
typedef __attribute__((ext_vector_type(8))) unsigned short u16x8;
typedef __attribute__((ext_vector_type(4))) float f32x4;

#define MFMA16(a, b, c) __builtin_amdgcn_mfma_f32_16x16x32_bf16(a, b, c, 0, 0, 0)

__device__ __forceinline__ u16 f2bf(float f) {
  unsigned u = __float_as_uint(f);
  u += 0x7fffu + ((u >> 16) & 1u);
  return (u16)(u >> 16);
}
__device__ __forceinline__ float bf2f(u16 u) {
  return __uint_as_float(((unsigned)u) << 16);
}

// async global->LDS, 16B per lane. lds ptr must be wave-uniform base; HW adds lane*16.
__device__ __forceinline__ void gl_lds16(const void* g, void* l) {
  __builtin_amdgcn_global_load_lds(
      (const __attribute__((address_space(1))) unsigned int*)g,
      (__attribute__((address_space(3))) unsigned int*)l, 16, 0, 0);
}

// ---------------------------------------------------------------------------
// hidden (HID x SQ) f32  ->  ht (SQ x HID) bf16   (transpose + convert)
__global__ __launch_bounds__(256) void k_ht(const float* __restrict__ hs,
                                            u16* __restrict__ ht) {
  __shared__ float tl[64][65];
  const int i0 = blockIdx.x << 6, s0 = blockIdx.y << 6;
  const int tid = threadIdx.x;
  {
    const int r = tid >> 2, c = (tid & 3) << 4;
    const float* p = hs + (i0 + r) * SQ_ + s0 + c;
    float4 a = *(const float4*)p;
    float4 b = *(const float4*)(p + 4);
    float4 cc = *(const float4*)(p + 8);
    float4 d = *(const float4*)(p + 12);
    float* q = &tl[r][c];
    q[0] = a.x; q[1] = a.y; q[2] = a.z; q[3] = a.w;
    q[4] = b.x; q[5] = b.y; q[6] = b.z; q[7] = b.w;
    q[8] = cc.x; q[9] = cc.y; q[10] = cc.z; q[11] = cc.w;
    q[12] = d.x; q[13] = d.y; q[14] = d.z; q[15] = d.w;
  }
  __syncthreads();
  {
    const int sr = tid >> 2, c = (tid & 3) << 4;
    u16x8 o0, o1;
#pragma unroll
    for (int j = 0; j < 8; ++j) o0[j] = f2bf(tl[c + j][sr]);
#pragma unroll
    for (int j = 0; j < 8; ++j) o1[j] = f2bf(tl[c + 8 + j][sr]);
    u16* q = ht + (s0 + sr) * HID_ + i0 + c;
    *(u16x8*)q = o0;
    *(u16x8*)(q + 8) = o1;
  }
}

// ---------------------------------------------------------------------------
// weight fp32 -> bf16, vectorized grid-stride (n8 = elements/8)
__global__ __launch_bounds__(256) void k_wconv(const float* __restrict__ s,
                                               u16* __restrict__ d, int n8) {
  const int stride = gridDim.x << 8;
  for (int i = (blockIdx.x << 8) + threadIdx.x; i < n8; i += stride) {
    const float4 a = ((const float4*)s)[2 * i];
    const float4 b = ((const float4*)s)[2 * i + 1];
    u16x8 o;
    o[0] = f2bf(a.x); o[1] = f2bf(a.y); o[2] = f2bf(a.z); o[3] = f2bf(a.w);
    o[4] = f2bf(b.x); o[5] = f2bf(b.y); o[6] = f2bf(b.z); o[7] = f2bf(b.w);
    ((u16x8*)d)[i] = o;
  }
}

// ---------------------------------------------------------------------------
// bf16 GEMM, m97 structure: C[m][n] = sum_k A[m][k]*B[n][k] (+bias[m])
// OUTMODE 0: bf16 out; 1: bf16 out at col offset cp; 2: f32 out
template <int OUTMODE>
__global__ __launch_bounds__(256) void k_gemm_bf(const u16* __restrict__ A,
                                                 const float* __restrict__ bias,
                                                 const u16* __restrict__ B,
                                                 void* __restrict__ Cout,
                                                 const int* __restrict__ cpp,
                                                 int ldc) {
  __shared__ u16 a_t[128 * 32];
  __shared__ u16 b_t[128 * 32];
  const int n0 = blockIdx.x << 7, m0 = blockIdx.y << 7;
  const int tid = threadIdx.x, wid = tid >> 6, lane = tid & 63;
  const int l15 = lane & 15, l4 = lane >> 4;
  const int wm = (wid >> 1) << 6, wn = (wid & 1) << 6;
  const f32x4 z4 = {0.f, 0.f, 0.f, 0.f};
  f32x4 acc[4][4];
#pragma unroll
  for (int i = 0; i < 4; ++i)
#pragma unroll
    for (int j = 0; j < 4; ++j) acc[i][j] = z4;

  // staging: LDS byte b = j*4096 + wid*1024 + lane*16 ; row=b>>6, colb=b&63
  const int r_ = (wid << 4) + (lane >> 2);
  const int cb = (lane & 3) << 4;
  const char* Ag0 = (const char*)A + (((size_t)(m0 + r_) * HID_) << 1) + cb;
  const char* Ag1 = Ag0 + ((size_t)64 * HID_ << 1);
  const char* Bg0 = (const char*)B + (((size_t)(n0 + r_) * HID_) << 1) + cb;
  const char* Bg1 = Bg0 + ((size_t)64 * HID_ << 1);
  u16* la0 = a_t + (wid << 9);
  u16* la1 = la0 + 2048;
  u16* lb0 = b_t + (wid << 9);
  u16* lb1 = lb0 + 2048;

  for (int kt = 0; kt < HID_ / 32; ++kt) {
    __syncthreads();  // all waves done reading previous tile
    gl_lds16(Ag0, la0);
    gl_lds16(Ag1, la1);
    gl_lds16(Bg0, lb0);
    gl_lds16(Bg1, lb1);
    Ag0 += 64; Ag1 += 64; Bg0 += 64; Bg1 += 64;
    __syncthreads();  // compiler drains vmcnt(0) here -> LDS ready
    bf16x8 af[4];
#pragma unroll
    for (int mf = 0; mf < 4; ++mf)
      af[mf] = *(const bf16x8*)&a_t[((wm + mf * 16 + l15) << 5) + (l4 << 3)];
#pragma unroll
    for (int nf = 0; nf < 4; ++nf) {
      bf16x8 bf = *(const bf16x8*)&b_t[((wn + nf * 16 + l15) << 5) + (l4 << 3)];
#pragma unroll
      for (int mf = 0; mf < 4; ++mf) acc[mf][nf] = MFMA16(af[mf], bf, acc[mf][nf]);
    }
  }

  const int coff = (OUTMODE == 1) ? cpp[0] : 0;
#pragma unroll
  for (int mf = 0; mf < 4; ++mf) {
#pragma unroll
    for (int r = 0; r < 4; ++r) {
      const int m = m0 + wm + mf * 16 + (l4 << 2) + r;
      const float bi = bias ? bias[m] : 0.f;
#pragma unroll
      for (int nf = 0; nf < 4; ++nf) {
        const int n = n0 + wn + nf * 16 + l15;
        const float v = acc[mf][nf][r] + bi;
        if (OUTMODE == 2)
          ((float*)Cout)[(size_t)m * ldc + n] = v;
        else
          ((u16*)Cout)[(size_t)m * ldc + n + coff] = f2bf(v);
      }
    }
  }
}

// ---------------------------------------------------------------------------
// fallback GEMM (fp32 A with fused convert) — used if workspace too small
template <int OUTMODE>
__global__ __launch_bounds__(256) void k_gemm_f32A(const float* __restrict__ A,
                                                   const float* __restrict__ bias,
                                                   const u16* __restrict__ B,
                                                   void* __restrict__ Cout,
                                                   const int* __restrict__ cpp,
                                                   int ldc) {
  __shared__ u16 a_t[128 * 32];
  __shared__ u16 b_t[128 * 32];
  const int n0 = blockIdx.x << 7, m0 = blockIdx.y << 7;
  const int tid = threadIdx.x;
  const int wid = tid >> 6, lane = tid & 63;
  const int l15 = lane & 15, l4 = lane >> 4;
  const int wm = (wid >> 1) * 64, wn = (wid & 1) * 64;
  const f32x4 z4 = {0.f, 0.f, 0.f, 0.f};
  f32x4 acc[4][4];
#pragma unroll
  for (int i = 0; i < 4; ++i)
#pragma unroll
    for (int j = 0; j < 4; ++j) acc[i][j] = z4;
  const int arow = tid >> 1, ac = (tid & 1) << 4;
  const float* Ap = A + (size_t)(m0 + arow) * HID_ + ac;
  const u16* Bp = B + (size_t)(n0 + arow) * HID_ + ac;
  for (int kt = 0; kt < HID_ / 32; ++kt) {
    float4 f0 = *(const float4*)(Ap);
    float4 f1 = *(const float4*)(Ap + 4);
    float4 f2 = *(const float4*)(Ap + 8);
    float4 f3 = *(const float4*)(Ap + 12);
    uint4 b0 = *(const uint4*)(Bp);
    uint4 b1 = *(const uint4*)(Bp + 8);
    Ap += 32;
    Bp += 32;
    u16x8 ua0, ua1;
    ua0[0] = f2bf(f0.x); ua0[1] = f2bf(f0.y); ua0[2] = f2bf(f0.z); ua0[3] = f2bf(f0.w);
    ua0[4] = f2bf(f1.x); ua0[5] = f2bf(f1.y); ua0[6] = f2bf(f1.z); ua0[7] = f2bf(f1.w);
    ua1[0] = f2bf(f2.x); ua1[1] = f2bf(f2.y); ua1[2] = f2bf(f2.z); ua1[3] = f2bf(f2.w);
    ua1[4] = f2bf(f3.x); ua1[5] = f2bf(f3.y); ua1[6] = f2bf(f3.z); ua1[7] = f2bf(f3.w);
    __syncthreads();
    *(u16x8*)&a_t[arow * 32 + ac] = ua0;
    *(u16x8*)&a_t[arow * 32 + ac + 8] = ua1;
    *(uint4*)&b_t[arow * 32 + ac] = b0;
    *(uint4*)&b_t[arow * 32 + ac + 8] = b1;
    __syncthreads();
    bf16x8 af[4];
#pragma unroll
    for (int mf = 0; mf < 4; ++mf)
      af[mf] = *(const bf16x8*)&a_t[(wm + mf * 16 + l15) * 32 + l4 * 8];
#pragma unroll
    for (int nf = 0; nf < 4; ++nf) {
      bf16x8 bf = *(const bf16x8*)&b_t[(wn + nf * 16 + l15) * 32 + l4 * 8];
#pragma unroll
      for (int mf = 0; mf < 4; ++mf) acc[mf][nf] = MFMA16(af[mf], bf, acc[mf][nf]);
    }
  }
  const int coff = (OUTMODE == 1) ? cpp[0] : 0;
#pragma unroll
  for (int mf = 0; mf < 4; ++mf) {
#pragma unroll
    for (int r = 0; r < 4; ++r) {
      const int m = m0 + wm + mf * 16 + l4 * 4 + r;
      const float bi = bias ? bias[m] : 0.f;
#pragma unroll
      for (int nf = 0; nf < 4; ++nf) {
        const int n = n0 + wn + nf * 16 + l15;
        const float v = acc[mf][nf][r] + bi;
        if (OUTMODE == 2)
          ((float*)Cout)[(size_t)m * ldc + n] = v;
        else
          ((u16*)Cout)[(size_t)m * ldc + n + coff] = f2bf(v);
      }
    }
  }
}

// ---------------------------------------------------------------------------
// RoPE on q (rotate along d, tables cos_t/sin_t are [d][s]), transpose to (h,s,d)
__global__ __launch_bounds__(256) void k_rope_q(const u16* __restrict__ qnr,
                                                const float* __restrict__ cost,
                                                const float* __restrict__ sint,
                                                u16* __restrict__ Qr) {
  __shared__ u16 qt[128 * 64];
  __shared__ float ct[128 * 64];
  __shared__ float st[128 * 64];
  const int s0 = blockIdx.x << 6, h = blockIdx.y;
  const int tid = threadIdx.x;
  {
    const int r = tid >> 1, c = (tid & 1) << 5;
    const u16* p = qnr + (h * 128 + r) * SQ_ + s0 + c;
#pragma unroll
    for (int j = 0; j < 4; ++j) *(uint4*)&qt[r * 64 + c + j * 8] = *(const uint4*)(p + j * 8);
    const float* cpr = cost + r * SQ_ + s0 + c;
    const float* spr = sint + r * SQ_ + s0 + c;
#pragma unroll
    for (int j = 0; j < 8; ++j) {
      *(float4*)&ct[r * 64 + c + j * 4] = *(const float4*)(cpr + j * 4);
      *(float4*)&st[r * 64 + c + j * 4] = *(const float4*)(spr + j * 4);
    }
  }
  __syncthreads();
  const int sl = tid >> 2, d0 = (tid & 3) << 5;
  u16* op = Qr + (((h << 10) + s0 + sl) << 7) + d0;
#pragma unroll
  for (int g = 0; g < 4; ++g) {
    u16x8 o;
#pragma unroll
    for (int j = 0; j < 8; ++j) {
      const int d = d0 + g * 8 + j;
      const float v = bf2f(qt[d * 64 + sl]);
      const float vp = bf2f(qt[(d ^ 64) * 64 + sl]);
      const float sgn = (d < 64) ? -1.f : 1.f;
      o[j] = f2bf(v * ct[d * 64 + sl] + sgn * vp * st[d * 64 + sl]);
    }
    *(u16x8*)(op + g * 8) = o;
  }
}

// RoPE on k (tables cos/sin are [s][d]), scatter to k_full[kk][cp+s][d]
__global__ __launch_bounds__(256) void k_rope_k(const u16* __restrict__ knr,
                                                const float* __restrict__ cosp,
                                                const float* __restrict__ sinp,
                                                const int* __restrict__ cpp,
                                                u16* __restrict__ kful) {
  __shared__ u16 kt_[128 * 64];
  const int s0 = blockIdx.x << 6, kk = blockIdx.y;
  const int cp = cpp[0];
  const int tid = threadIdx.x;
  {
    const int r = tid >> 1, c = (tid & 1) << 5;
    const u16* p = knr + (kk * 128 + r) * SQ_ + s0 + c;
#pragma unroll
    for (int j = 0; j < 4; ++j) *(uint4*)&kt_[r * 64 + c + j * 8] = *(const uint4*)(p + j * 8);
  }
  __syncthreads();
  const int sl = tid >> 2, d0 = (tid & 3) << 5;
  const int s = s0 + sl;
  const float* crow = cosp + s * D_;
  const float* srow = sinp + s * D_;
  u16* op = kful + ((kk * SMAX_ + cp + s) << 7) + d0;
#pragma unroll
  for (int g = 0; g < 4; ++g) {
    u16x8 o;
#pragma unroll
    for (int j = 0; j < 8; ++j) {
      const int d = d0 + g * 8 + j;
      const float v = bf2f(kt_[d * 64 + sl]);
      const float vp = bf2f(kt_[(d ^ 64) * 64 + sl]);
      const float sgn = (d < 64) ? -1.f : 1.f;
      o[j] = f2bf(v * crow[d] + sgn * vp * srow[d]);
    }
    *(u16x8*)(op + g * 8) = o;
  }
}

// key_cache[0] prefix (s<cp) -> k_full bf16 (same layout)
__global__ __launch_bounds__(256) void k_prefk(const float* __restrict__ kc,
                                               const int* __restrict__ cpp,
                                               u16* __restrict__ kful) {
  const int cp = cpp[0];
  const int idx = (blockIdx.x << 8) + threadIdx.x;
  const int base = idx << 3;
  const int s = (base >> 7) & (SMAX_ - 1);
  if (s >= cp) return;
  const float* p = kc + base;
  float4 a = *(const float4*)p;
  float4 b = *(const float4*)(p + 4);
  u16x8 o;
  o[0] = f2bf(a.x); o[1] = f2bf(a.y); o[2] = f2bf(a.z); o[3] = f2bf(a.w);
  o[4] = f2bf(b.x); o[5] = f2bf(b.y); o[6] = f2bf(b.z); o[7] = f2bf(b.w);
  *(u16x8*)(kful + base) = o;
}

// value_cache[0] prefix (s<cp) -> v_t[kk][d][s] bf16 (transposed)
__global__ __launch_bounds__(256) void k_prefvt(const float* __restrict__ vc,
                                                const int* __restrict__ cpp,
                                                u16* __restrict__ vt) {
  const int cp = cpp[0];
  const int s0 = blockIdx.x << 6, d0 = blockIdx.y << 6, kk = blockIdx.z;
  if (s0 >= cp) return;
  __shared__ float tl[64][65];
  const int tid = threadIdx.x;
  {
    const int r = tid >> 2, c = (tid & 3) << 4;
    if (s0 + r < cp) {
      const float* p = vc + ((kk * SMAX_ + s0 + r) << 7) + d0 + c;
#pragma unroll
      for (int j = 0; j < 4; ++j) {
        float4 v = *(const float4*)(p + j * 4);
        tl[r][c + j * 4 + 0] = v.x;
        tl[r][c + j * 4 + 1] = v.y;
        tl[r][c + j * 4 + 2] = v.z;
        tl[r][c + j * 4 + 3] = v.w;
      }
    }
  }
  __syncthreads();
  const int dl = tid >> 2, c = (tid & 3) << 4;
  u16* op = vt + (kk * D_ + d0 + dl) * SMAX_ + s0 + c;
  if (s0 + c + 15 < cp) {
    u16x8 o0, o1;
#pragma unroll
    for (int j = 0; j < 8; ++j) o0[j] = f2bf(tl[c + j][dl]);
#pragma unroll
    for (int j = 0; j < 8; ++j) o1[j] = f2bf(tl[c + 8 + j][dl]);
    *(u16x8*)op = o0;
    *(u16x8*)(op + 8) = o1;
  } else {
#pragma unroll
    for (int j = 0; j < 16; ++j)
      if (s0 + c + j < cp) op[j] = f2bf(tl[c + j][dl]);
  }
}

// ---------------------------------------------------------------------------
// K/V staging for attn: linear LDS dest, pre-swizzled global source.
// K tile: [64][128] bf16 (16KB), swizzle byte ^= ((row&7)<<4), row = byte>>8
// V tile: [128][64] bf16 (16KB), swizzle byte ^= ((row&7)<<4), row = byte>>7
__device__ __forceinline__ void attn_stage(const char* KfB, const char* VtB, int kv0,
                                           u16* kbuf, u16* vbuf, int wid, int lane) {
  const int kr = (wid << 2) + (lane >> 4);
  const int kcb = (lane & 15) << 4;
  const int vr = (wid << 3) + (lane >> 3);
  const int vcb = (lane & 7) << 4;
#pragma unroll
  for (int j = 0; j < 4; ++j) {
    const int row = (j << 4) + kr;
    gl_lds16(KfB + (((size_t)(kv0 + row)) << 8) + (kcb ^ ((row & 7) << 4)),
             kbuf + (j << 11) + (wid << 9));
  }
#pragma unroll
  for (int j = 0; j < 4; ++j) {
    const int row = (j << 5) + vr;
    gl_lds16(VtB + ((((size_t)row * SMAX_) + kv0) << 1) + (vcb ^ ((row & 7) << 4)),
             vbuf + (j << 11) + (wid << 9));
  }
}

// Flash attention v2: block = (head, 64-q-rows), 4 waves x 16 rows,
// KV tiles of 64 double-buffered in LDS, 2-phase pipeline.
__global__ __launch_bounds__(256) void k_attn(const u16* __restrict__ Q,
                                              const u16* __restrict__ Kf,
                                              const u16* __restrict__ Vt,
                                              const int* __restrict__ cpp,
                                              u16* __restrict__ Ob) {
  __shared__ u16 Kb[2][8192];
  __shared__ u16 Vb[2][8192];
  __shared__ u16 Pl[4][1024];
  const int h = blockIdx.x, qb = blockIdx.y;
  const int cp = cpp[0];
  const int kk = h >> 4;
  const int tid = threadIdx.x, wid = tid >> 6, lane = tid & 63;
  const int l15 = lane & 15, l4 = lane >> 4;
  const int qrow_base = (qb << 6) + (wid << 4);
  char* pl = (char*)&Pl[wid][0];

  bf16x8 aq[4];
#pragma unroll
  for (int ks = 0; ks < 4; ++ks)
    aq[ks] = *(const bf16x8*)&Q[(((size_t)(h << 10) + qrow_base + l15) << 7) + ks * 32 + (l4 << 3)];

  const f32x4 z4 = {0.f, 0.f, 0.f, 0.f};
  f32x4 oacc[8];
  float mrun[4], lrun[4];
#pragma unroll
  for (int nf = 0; nf < 8; ++nf) oacc[nf] = z4;
#pragma unroll
  for (int r = 0; r < 4; ++r) { mrun[r] = -1e30f; lrun[r] = 0.f; }

  const int nt0 = ((cp + (qb << 6) + 63) >> 6) + 1;
  const int nt = nt0 < (SMAX_ >> 6) ? nt0 : (SMAX_ >> 6);
  const float sc = 0.08838834764831845f;  // 1/sqrt(128)

  const char* KfB = (const char*)Kf + ((size_t)kk * SMAX_ << 8);
  const char* VtB = (const char*)Vt + ((size_t)kk * 128 * SMAX_ << 1);

  attn_stage(KfB, VtB, 0, Kb[0], Vb[0], wid, lane);
  __syncthreads();  // vmcnt(0) drain + barrier
  int cur = 0;

  for (int kt = 0; kt < nt; ++kt) {
    const int kv0 = kt << 6;
    if (kt + 1 < nt) attn_stage(KfB, VtB, kv0 + 64, Kb[cur ^ 1], Vb[cur ^ 1], wid, lane);

    const char* kb = (const char*)Kb[cur];
    const char* vb = (const char*)Vb[cur];
    // ---- QK^T ----
    f32x4 sa[4];
#pragma unroll
    for (int nf = 0; nf < 4; ++nf) sa[nf] = z4;
#pragma unroll
    for (int ks = 0; ks < 4; ++ks) {
#pragma unroll
      for (int nf = 0; nf < 4; ++nf) {
        const int rk = nf * 16 + l15;
        bf16x8 bk = *(const bf16x8*)(kb + (((rk << 8) + (ks << 6) + (l4 << 4)) ^ ((rk & 7) << 4)));
        sa[nf] = MFMA16(aq[ks], bk, sa[nf]);
      }
    }
    // ---- online softmax (defer-max) ----
    const bool needmask = (kv0 + 63) > (cp + qrow_base);
#pragma unroll
    for (int r = 0; r < 4; ++r) {
      const int row = (l4 << 2) + r;
      const int lim = cp + qrow_base + row;
      float x0 = sa[0][r] * sc, x1 = sa[1][r] * sc, x2 = sa[2][r] * sc, x3 = sa[3][r] * sc;
      if (needmask) {
        if (kv0 + 0 + l15 > lim) x0 = -1e9f;
        if (kv0 + 16 + l15 > lim) x1 = -1e9f;
        if (kv0 + 32 + l15 > lim) x2 = -1e9f;
        if (kv0 + 48 + l15 > lim) x3 = -1e9f;
      }
      float pm = fmaxf(fmaxf(x0, x1), fmaxf(x2, x3));
      pm = fmaxf(pm, __shfl_xor(pm, 1));
      pm = fmaxf(pm, __shfl_xor(pm, 2));
      pm = fmaxf(pm, __shfl_xor(pm, 4));
      pm = fmaxf(pm, __shfl_xor(pm, 8));
      const float mold = mrun[r];
      const bool need = pm > mold + 8.f;
      const float mnew = need ? pm : mold;
      const float p0 = __expf(x0 - mnew), p1 = __expf(x1 - mnew);
      const float p2 = __expf(x2 - mnew), p3 = __expf(x3 - mnew);
      float rs = p0 + p1 + p2 + p3;
      rs += __shfl_xor(rs, 1);
      rs += __shfl_xor(rs, 2);
      rs += __shfl_xor(rs, 4);
      rs += __shfl_xor(rs, 8);
      if (need) {
        const float sf = __expf(mold - mnew);
        lrun[r] = lrun[r] * sf + rs;
        mrun[r] = mnew;
#pragma unroll
        for (int nf = 0; nf < 8; ++nf) oacc[nf][r] *= sf;
      } else {
        lrun[r] += rs;
      }
      const unsigned sw = (unsigned)((row & 7) << 4);
      const unsigned rb = (unsigned)(row << 7);
      *(u16*)(pl + ((rb + (unsigned)((0 + l15) << 1)) ^ sw)) = f2bf(p0);
      *(u16*)(pl + ((rb + (unsigned)((16 + l15) << 1)) ^ sw)) = f2bf(p1);
      *(u16*)(pl + ((rb + (unsigned)((32 + l15) << 1)) ^ sw)) = f2bf(p2);
      *(u16*)(pl + ((rb + (unsigned)((48 + l15) << 1)) ^ sw)) = f2bf(p3);
    }
    // ---- P fragments ----
    bf16x8 ap[2];
#pragma unroll
    for (int k2 = 0; k2 < 2; ++k2) {
      const unsigned byte = (unsigned)(((l15 << 7) + (k2 << 6) + (l4 << 4)) ^ ((l15 & 7) << 4));
      ap[k2] = *(const bf16x8*)(pl + byte);
    }
    // ---- PV ----
#pragma unroll
    for (int nf = 0; nf < 8; ++nf) {
#pragma unroll
      for (int k2 = 0; k2 < 2; ++k2) {
        const int rv = nf * 16 + l15;
        bf16x8 bv = *(const bf16x8*)(vb + (((rv << 7) + (k2 << 6) + (l4 << 4)) ^ ((rv & 7) << 4)));
        oacc[nf] = MFMA16(ap[k2], bv, oacc[nf]);
      }
    }
    __syncthreads();  // drains next-tile stage loads + syncs buffer swap
    cur ^= 1;
  }

#pragma unroll
  for (int r = 0; r < 4; ++r) {
    const float inv = 1.f / lrun[r];
    const int qrow = qrow_base + (l4 << 2) + r;
#pragma unroll
    for (int nf = 0; nf < 8; ++nf)
      Ob[((size_t)qrow << 12) + (h << 7) + nf * 16 + l15] = f2bf(oacc[nf][r] * inv);
  }
}

// ---------------------------------------------------------------------------
extern "C" void kernel_launch(void* const* d_in, const int* in_sizes, int n_in,
                              void* d_out, int out_size, void* d_ws, size_t ws_size,
                              hipStream_t stream) {
  const float* hs    = (const float*)d_in[0];
  const float* cosp  = (const float*)d_in[1];
  const float* sinp  = (const float*)d_in[2];
  const float* cost  = (const float*)d_in[3];
  const float* sint  = (const float*)d_in[4];
  // d_in[5] attention_mask: analytically reproduced (kv <= cp + q -> 0 else -1e9)
  const float* kcache = (const float*)d_in[6];
  const float* vcache = (const float*)d_in[7];
  const float* wq = (const float*)d_in[8];
  const float* bq = (const float*)d_in[9];
  const float* wk = (const float*)d_in[10];
  const float* bk = (const float*)d_in[11];
  const float* wv = (const float*)d_in[12];
  const float* bv = (const float*)d_in[13];
  const float* wo = (const float*)d_in[14];
  const int* cpp = (const int*)d_in[15];

  char* ws = (char*)d_ws;
  u16* ht   = (u16*)(ws);                       //  8.0 MB : hidden^T bf16 (SQ x HID)
  u16* qnr  = (u16*)(ws + 8388608);             //  8.0 MB : q pre-rope (HD x SQ)
  u16* Qr   = (u16*)(ws + 16777216);            //  8.0 MB : q roped (H,SQ,D)
  u16* knr  = (u16*)(ws + 25165824);            //  0.5 MB : k pre-rope (256 x SQ)
  u16* kful = (u16*)(ws + 25690112);            //  2.0 MB : K full (KV,SMAX,D)
  u16* vt   = (u16*)(ws + 27787264);            //  2.0 MB : V^T full (KV,D,SMAX)
  u16* Ob   = (u16*)(ws + 29884416);            //  8.0 MB : attn out (SQ x HD)

  const size_t WOFF  = 38273024;
  const size_t SZ_WQ = (size_t)H_ * D_ * HID_ * 2;   // 37748736
  const size_t SZ_WK = (size_t)KV_ * D_ * HID_ * 2;  //  2097152
  const size_t SZ_WO = (size_t)HID_ * H_ * D_ * 2;   // 33554432
  const bool pre = ws_size >= WOFF + SZ_WQ + 2 * SZ_WK + SZ_WO;

  k_ht<<<dim3(64, 16), 256, 0, stream>>>(hs, ht);
  if (pre) {
    u16* wqb = (u16*)(ws + WOFF);
    u16* wkb = (u16*)(ws + WOFF + SZ_WQ);
    u16* wvb = (u16*)(ws + WOFF + SZ_WQ + SZ_WK);
    u16* wob = (u16*)(ws + WOFF + SZ_WQ + 2 * SZ_WK);
    k_wconv<<<2048, 256, 0, stream>>>(wq, wqb, (int)(H_ * D_ * HID_ / 8));
    k_wconv<<<256, 256, 0, stream>>>(wk, wkb, (int)(KV_ * D_ * HID_ / 8));
    k_wconv<<<256, 256, 0, stream>>>(wv, wvb, (int)(KV_ * D_ * HID_ / 8));
    k_wconv<<<2048, 256, 0, stream>>>(wo, wob, (int)(HID_ * H_ * D_ / 8));
    k_gemm_bf<0><<<dim3(8, 32), 256, 0, stream>>>(wqb, bq, ht, (void*)qnr, nullptr, SQ_);
    k_gemm_bf<0><<<dim3(8, 2), 256, 0, stream>>>(wkb, bk, ht, (void*)knr, nullptr, SQ_);
    k_gemm_bf<1><<<dim3(8, 2), 256, 0, stream>>>(wvb, bv, ht, (void*)vt, cpp, SMAX_);
    k_rope_q<<<dim3(16, 32), 256, 0, stream>>>(qnr, cost, sint, Qr);
    k_rope_k<<<dim3(16, 2), 256, 0, stream>>>(knr, cosp, sinp, cpp, kful);
    k_prefk<<<dim3(512), 256, 0, stream>>>(kcache, cpp, kful);
    k_prefvt<<<dim3(64, 2, 2), 256, 0, stream>>>(vcache, cpp, vt);
    k_attn<<<dim3(32, 16), 256, 0, stream>>>(Qr, kful, vt, cpp, Ob);
    k_gemm_bf<2><<<dim3(8, 32), 256, 0, stream>>>(wob, nullptr, Ob, d_out, nullptr, SQ_);
  } else {
    k_gemm_f32A<0><<<dim3(8, 32), 256, 0, stream>>>(wq, bq, ht, (void*)qnr, nullptr, SQ_);
    k_gemm_f32A<0><<<dim3(8, 2), 256, 0, stream>>>(wk, bk, ht, (void*)knr, nullptr, SQ_);
    k_gemm_f32A<1><<<dim3(8, 2), 256, 0, stream>>>(wv, bv, ht, (void*)vt, cpp, SMAX_);
    k_rope_q<<<dim3(16, 32), 256, 0, stream>>>(qnr, cost, sint, Qr);
    k_rope_k<<<dim3(16, 2), 256, 0, stream>>>(knr, cosp, sinp, cpp, kful);
    k_prefk<<<dim3(512), 256, 0, stream>>>(kcache, cpp, kful);
    k_prefvt<<<dim3(64, 2, 2), 256, 0, stream>>>(vcache, cpp, vt);
    k_attn<<<dim3(32, 16), 256, 0, stream>>>(Qr, kful, vt, cpp, Ob);
    k_gemm_f32A<2><<<dim3(8, 32), 256, 0, stream>>>(wo, nullptr, Ob, d_out, nullptr, SQ_);
  }
  (void)in_sizes; (void)n_in; (void)out_size; (void)ws_size;
}